// Round 1
// baseline (445.119 us; speedup 1.0000x reference)
//
#include <hip/hip_runtime.h>
#include <hip/hip_bf16.h>

#define HW 3600
#define NQ 28800
#define CIN 256
#define CMID 128

typedef short bf16x8 __attribute__((ext_vector_type(8)));
typedef float f32x4 __attribute__((ext_vector_type(4)));

__device__ inline unsigned short f2bf(float f) {
  unsigned u = __float_as_uint(f);
  unsigned r = (u + 0x7fffu + ((u >> 16) & 1u)) >> 16;   // round-to-nearest-even
  return (unsigned short)r;
}
__device__ inline float bflo(unsigned u) { return __uint_as_float(u << 16); }
__device__ inline float bfhi(unsigned u) { return __uint_as_float(u & 0xffff0000u); }

// ---------------- transpose weights once: conv_w [128][256] -> cw_t [256][128]
__global__ void transpose_w_kernel(const float* __restrict__ conv_w,
                                   const float* __restrict__ lin_w,
                                   float* __restrict__ cw_t, float* __restrict__ lw_t) {
  const int i = blockIdx.x * 256 + threadIdx.x;
  if (i < 128 * 256) { const int co = i >> 8, ci = i & 255; cw_t[ci * 128 + co] = conv_w[i]; }
  if (i < 128 * 128) { const int o = i >> 7, c = i & 127; lw_t[c * 128 + o] = lin_w[i]; }
}

// ---------------- conv1: y[co][b*HW+p] = sum_ci W[co][ci]*relu(x[b][ci][p]) + b[co]
__global__ __launch_bounds__(256) void conv1_kernel(
    const float* __restrict__ x, const float* __restrict__ cw_t,
    const float* __restrict__ conv_b, float* __restrict__ y) {
  __shared__ __align__(16) float ws[32 * 128];
  __shared__ __align__(16) float xs[32 * 64];
  const int b = blockIdx.y;
  const int p0 = blockIdx.x * 64;
  const int t = threadIdx.x;
  const int tp = t & 15;   // p = p0 + tp*4 + j
  const int tc = t >> 4;   // co = tc*8 + i
  float acc[8][4];
#pragma unroll
  for (int i = 0; i < 8; i++)
#pragma unroll
    for (int j = 0; j < 4; j++) acc[i][j] = 0.f;
  const float* xb = x + (size_t)b * CIN * HW;
  for (int c0 = 0; c0 < CIN; c0 += 32) {
    __syncthreads();
#pragma unroll
    for (int rep = 0; rep < 4; rep++) {
      int lin = rep * 1024 + t * 4;
      int cc = lin >> 7, co = lin & 127;
      *(float4*)&ws[lin] = *(const float4*)&cw_t[(c0 + cc) * 128 + co];
    }
#pragma unroll
    for (int rep = 0; rep < 2; rep++) {
      int lin = rep * 1024 + t * 4;
      int cc = lin >> 6, pp = lin & 63;
      int p = p0 + pp;
      float4 v = make_float4(0.f, 0.f, 0.f, 0.f);
      if (p < HW) v = *(const float4*)&xb[(size_t)(c0 + cc) * HW + p];
      v.x = fmaxf(v.x, 0.f); v.y = fmaxf(v.y, 0.f);
      v.z = fmaxf(v.z, 0.f); v.w = fmaxf(v.w, 0.f);
      *(float4*)&xs[lin] = v;
    }
    __syncthreads();
#pragma unroll
    for (int cc = 0; cc < 32; cc++) {
      float wv[8], xv[4];
      *(float4*)&wv[0] = *(const float4*)&ws[cc * 128 + tc * 8];
      *(float4*)&wv[4] = *(const float4*)&ws[cc * 128 + tc * 8 + 4];
      *(float4*)&xv[0] = *(const float4*)&xs[cc * 64 + tp * 4];
#pragma unroll
      for (int i = 0; i < 8; i++)
#pragma unroll
        for (int j = 0; j < 4; j++) acc[i][j] = fmaf(wv[i], xv[j], acc[i][j]);
    }
  }
  const int p = p0 + tp * 4;
  if (p < HW) {
#pragma unroll
    for (int i = 0; i < 8; i++) {
      const int co = tc * 8 + i;
      const float bias = conv_b[co];
      float4 v = make_float4(acc[i][0] + bias, acc[i][1] + bias,
                             acc[i][2] + bias, acc[i][3] + bias);
      *(float4*)&y[(size_t)co * NQ + b * HW + p] = v;
    }
  }
}

// ---------------- per-channel sum / sumsq over all 28800 positions
__global__ __launch_bounds__(256) void stats_kernel(const float* __restrict__ y,
                                                    float* __restrict__ stats) {
  const int c = blockIdx.x >> 1;
  const int half = blockIdx.x & 1;
  const float* row = y + (size_t)c * NQ + half * (NQ / 2);
  float s = 0.f, s2 = 0.f;
  for (int i = threadIdx.x * 4; i < NQ / 2; i += 256 * 4) {
    float4 v = *(const float4*)&row[i];
    s += v.x + v.y + v.z + v.w;
    s2 += v.x * v.x + v.y * v.y + v.z * v.z + v.w * v.w;
  }
#pragma unroll
  for (int m = 1; m < 64; m <<= 1) { s += __shfl_xor(s, m); s2 += __shfl_xor(s2, m); }
  __shared__ float red[8];
  const int wid = threadIdx.x >> 6;
  if ((threadIdx.x & 63) == 0) { red[wid] = s; red[4 + wid] = s2; }
  __syncthreads();
  if (threadIdx.x == 0) {
    atomicAdd(&stats[c], red[0] + red[1] + red[2] + red[3]);
    atomicAdd(&stats[128 + c], red[4] + red[5] + red[6] + red[7]);
  }
}

// ---------------- BN affine fold: s = gamma*rsqrt(var+eps), t = beta - mean*s
__global__ void scale_kernel(const float* __restrict__ stats, const float* __restrict__ gamma,
                             const float* __restrict__ beta, float* __restrict__ sc) {
  const int c = threadIdx.x;
  const float inv_n = 1.f / (float)NQ;
  float mean = stats[c] * inv_n;
  float var = stats[128 + c] * inv_n - mean * mean;
  float s = gamma[c] * rsqrtf(var + 1e-5f);
  sc[c] = s;
  sc[128 + c] = beta[c] - mean * s;
}

// ---------------- conv2 + L2-normalize + bf16 pack: feat[q][o]
__global__ __launch_bounds__(256) void conv2norm_kernel(
    const float* __restrict__ y, const float* __restrict__ lw_t,
    const float* __restrict__ sc, const float* __restrict__ lin_b,
    unsigned short* __restrict__ feat) {
  __shared__ __align__(16) float ws[32 * 128];
  __shared__ __align__(16) float xs[32 * 64];
  __shared__ float nsq[16][65];
  const int q0 = blockIdx.x * 64;
  const int t = threadIdx.x;
  const int tp = t & 15;   // q = q0 + tp*4 + j
  const int tc = t >> 4;   // o = tc*8 + i
  float acc[8][4];
#pragma unroll
  for (int i = 0; i < 8; i++)
#pragma unroll
    for (int j = 0; j < 4; j++) acc[i][j] = 0.f;
  for (int c0 = 0; c0 < CMID; c0 += 32) {
    __syncthreads();
#pragma unroll
    for (int rep = 0; rep < 4; rep++) {
      int lin = rep * 1024 + t * 4;
      int cc = lin >> 7, o = lin & 127;
      *(float4*)&ws[lin] = *(const float4*)&lw_t[(c0 + cc) * 128 + o];
    }
#pragma unroll
    for (int rep = 0; rep < 2; rep++) {
      int lin = rep * 1024 + t * 4;
      int cc = lin >> 6, qq = lin & 63;
      float4 v = *(const float4*)&y[(size_t)(c0 + cc) * NQ + q0 + qq];
      const float s = sc[c0 + cc];
      const float tt = sc[128 + c0 + cc];
      v.x = fmaxf(fmaf(v.x, s, tt), 0.f);
      v.y = fmaxf(fmaf(v.y, s, tt), 0.f);
      v.z = fmaxf(fmaf(v.z, s, tt), 0.f);
      v.w = fmaxf(fmaf(v.w, s, tt), 0.f);
      *(float4*)&xs[lin] = v;
    }
    __syncthreads();
#pragma unroll
    for (int cc = 0; cc < 32; cc++) {
      float wv[8], xv[4];
      *(float4*)&wv[0] = *(const float4*)&ws[cc * 128 + tc * 8];
      *(float4*)&wv[4] = *(const float4*)&ws[cc * 128 + tc * 8 + 4];
      *(float4*)&xv[0] = *(const float4*)&xs[cc * 64 + tp * 4];
#pragma unroll
      for (int i = 0; i < 8; i++)
#pragma unroll
        for (int j = 0; j < 4; j++) acc[i][j] = fmaf(wv[i], xv[j], acc[i][j]);
    }
  }
#pragma unroll
  for (int i = 0; i < 8; i++) {
    const float bias = lin_b[tc * 8 + i];
#pragma unroll
    for (int j = 0; j < 4; j++) acc[i][j] += bias;
  }
  float sq[4];
#pragma unroll
  for (int j = 0; j < 4; j++) {
    float v = 0.f;
#pragma unroll
    for (int i = 0; i < 8; i++) v += acc[i][j] * acc[i][j];
    sq[j] = v;
  }
  __syncthreads();
#pragma unroll
  for (int j = 0; j < 4; j++) nsq[tc][tp * 4 + j] = sq[j];
  __syncthreads();
#pragma unroll
  for (int j = 0; j < 4; j++) {
    float tot = 0.f;
#pragma unroll
    for (int k = 0; k < 16; k++) tot += nsq[k][tp * 4 + j];
    const float inv = 1.f / fmaxf(sqrtf(tot), 1e-12f);
    union { unsigned short u[8]; uint4 v; } pk;
#pragma unroll
    for (int i = 0; i < 8; i++) pk.u[i] = f2bf(acc[i][j] * inv);
    *(uint4*)&feat[(size_t)(q0 + tp * 4 + j) * 128 + tc * 8] = pk.v;
  }
}

// ---------------- InfoNCE: sumexp[b][r] += sum_c exp(dot(o_r,t_c)/T - 1/T)
__global__ __launch_bounds__(256) void infonce_kernel(
    const unsigned short* __restrict__ fo, const unsigned short* __restrict__ ft,
    float* __restrict__ sumexp) {
  const int b = blockIdx.z;
  const int r0 = blockIdx.x * 64;
  const int c0 = blockIdx.y * 64;
  const int t = threadIdx.x;
  const int w = t >> 6;
  const int lane = t & 63;
  const int lr = lane & 15;
  const int lk = (lane >> 4) * 8;
  const int ra = min(r0 + w * 16 + lr, HW - 1);
  const unsigned short* ap = fo + ((size_t)b * HW + ra) * 128 + lk;
  bf16x8 a[4];
#pragma unroll
  for (int kk = 0; kk < 4; kk++) a[kk] = *(const bf16x8*)(ap + kk * 32);
  f32x4 acc[4];
#pragma unroll
  for (int sub = 0; sub < 4; sub++) acc[sub] = (f32x4){0.f, 0.f, 0.f, 0.f};
#pragma unroll
  for (int sub = 0; sub < 4; sub++) {
    const int cb = min(c0 + sub * 16 + lr, HW - 1);
    const unsigned short* bp = ft + ((size_t)b * HW + cb) * 128 + lk;
#pragma unroll
    for (int kk = 0; kk < 4; kk++) {
      bf16x8 bv = *(const bf16x8*)(bp + kk * 32);
      acc[sub] = __builtin_amdgcn_mfma_f32_16x16x32_bf16(a[kk], bv, acc[sub], 0, 0, 0);
    }
  }
  const float INV_T = 14.285714285714286f;
  float rs[4] = {0.f, 0.f, 0.f, 0.f};
#pragma unroll
  for (int sub = 0; sub < 4; sub++) {
    const bool cv = (c0 + sub * 16 + lr) < HW;
#pragma unroll
    for (int i = 0; i < 4; i++)
      rs[i] += cv ? __expf(fmaf(acc[sub][i], INV_T, -INV_T)) : 0.f;
  }
#pragma unroll
  for (int i = 0; i < 4; i++) {
    float v = rs[i];
    v += __shfl_xor(v, 1); v += __shfl_xor(v, 2);
    v += __shfl_xor(v, 4); v += __shfl_xor(v, 8);
    rs[i] = v;
  }
  if (lr == 0) {
    const int g = lane >> 4;
#pragma unroll
    for (int i = 0; i < 4; i++) {
      const int r = r0 + w * 16 + g * 4 + i;
      if (r < HW) atomicAdd(&sumexp[b * HW + r], rs[i]);
    }
  }
}

// ---------------- final: mean over q of (log(sumexp)+1/T - dot(o_q,t_q)/T)
__global__ __launch_bounds__(256) void final_kernel(
    const float* __restrict__ sumexp, const unsigned short* __restrict__ fo,
    const unsigned short* __restrict__ ft, float* __restrict__ out) {
  const int q = blockIdx.x * 256 + threadIdx.x;
  const float INV_T = 14.285714285714286f;
  float val = 0.f;
  if (q < NQ) {
    const unsigned short* a = fo + (size_t)q * 128;
    const unsigned short* c = ft + (size_t)q * 128;
    float dot = 0.f;
#pragma unroll
    for (int k = 0; k < 128; k += 8) {
      uint4 ua = *(const uint4*)(a + k);
      uint4 ub = *(const uint4*)(c + k);
      dot += bflo(ua.x) * bflo(ub.x) + bfhi(ua.x) * bfhi(ub.x);
      dot += bflo(ua.y) * bflo(ub.y) + bfhi(ua.y) * bfhi(ub.y);
      dot += bflo(ua.z) * bflo(ub.z) + bfhi(ua.z) * bfhi(ub.z);
      dot += bflo(ua.w) * bflo(ub.w) + bfhi(ua.w) * bfhi(ub.w);
    }
    val = logf(sumexp[q]) + INV_T - dot * INV_T;
  }
#pragma unroll
  for (int m = 1; m < 64; m <<= 1) val += __shfl_xor(val, m);
  __shared__ float red[4];
  const int wid = threadIdx.x >> 6;
  if ((threadIdx.x & 63) == 0) red[wid] = val;
  __syncthreads();
  if (threadIdx.x == 0)
    atomicAdd(out, (red[0] + red[1] + red[2] + red[3]) * (1.f / (float)NQ));
}

extern "C" void kernel_launch(void* const* d_in, const int* in_sizes, int n_in,
                              void* d_out, int out_size, void* d_ws, size_t ws_size,
                              hipStream_t stream) {
  (void)in_sizes; (void)n_in; (void)out_size; (void)ws_size;
  const float* x_orig = (const float*)d_in[0];
  const float* x_trans = (const float*)d_in[1];
  const float* conv_w = (const float*)d_in[2];
  const float* conv_b = (const float*)d_in[3];
  const float* gamma = (const float*)d_in[4];
  const float* beta = (const float*)d_in[5];
  const float* lin_w = (const float*)d_in[6];
  const float* lin_b = (const float*)d_in[7];
  float* out = (float*)d_out;

  char* ws = (char*)d_ws;
  float* y = (float*)(ws + 0);                        // 14,745,600 B
  float* cw_t = (float*)(ws + 14745600);              //    131,072 B
  float* lw_t = (float*)(ws + 14876672);              //     65,536 B
  float* statsO = (float*)(ws + 14942208);            //      1,024 B
  float* statsT = (float*)(ws + 14943232);            //      1,024 B
  float* sumexp = (float*)(ws + 14944256);            //    115,200 B
  float* scaleO = (float*)(ws + 15059456);            //      1,024 B
  float* scaleT = (float*)(ws + 15060480);            //      1,024 B
  unsigned short* feat_o = (unsigned short*)(ws + 15061504); // 7,372,800 B
  unsigned short* feat_t = (unsigned short*)(ws + 22434304); // 7,372,800 B

  hipMemsetAsync(ws + 14942208, 0, 1024 + 1024 + 115200, stream);
  hipMemsetAsync(d_out, 0, sizeof(float), stream);

  transpose_w_kernel<<<128, 256, 0, stream>>>(conv_w, lin_w, cw_t, lw_t);

  conv1_kernel<<<dim3(57, 8), 256, 0, stream>>>(x_orig, cw_t, conv_b, y);
  stats_kernel<<<256, 256, 0, stream>>>(y, statsO);
  scale_kernel<<<1, 128, 0, stream>>>(statsO, gamma, beta, scaleO);
  conv2norm_kernel<<<450, 256, 0, stream>>>(y, lw_t, scaleO, lin_b, feat_o);

  conv1_kernel<<<dim3(57, 8), 256, 0, stream>>>(x_trans, cw_t, conv_b, y);
  stats_kernel<<<256, 256, 0, stream>>>(y, statsT);
  scale_kernel<<<1, 128, 0, stream>>>(statsT, gamma, beta, scaleT);
  conv2norm_kernel<<<450, 256, 0, stream>>>(y, lw_t, scaleT, lin_b, feat_t);

  infonce_kernel<<<dim3(57, 57, 8), 256, 0, stream>>>(feat_o, feat_t, sumexp);
  final_kernel<<<113, 256, 0, stream>>>(sumexp, feat_o, feat_t, out);
}

// Round 3
// 278.653 us; speedup vs baseline: 1.5974x; 1.5974x over previous
//
#include <hip/hip_runtime.h>
#include <hip/hip_bf16.h>

#define HW 3600
#define NQ 28800
#define CIN 256
#define CMID 128

typedef short bf16x8 __attribute__((ext_vector_type(8)));
typedef float f32x4 __attribute__((ext_vector_type(4)));

#define INV_T 14.285714285714286f
#define SQRT_INV_T 3.7796447300922722f
#define LOG2E 1.4426950408889634f
#define NM (-20.60992915555662f)   /* -INV_T*LOG2E */

__device__ inline unsigned short f2bf(float f) {
  unsigned u = __float_as_uint(f);
  return (unsigned short)((u + 0x7fffu + ((u >> 16) & 1u)) >> 16);  // RNE
}
__device__ inline float bf2f(unsigned short h) { return __uint_as_float((unsigned)h << 16); }

// ---------------- prep: fp32 weights -> bf16 (native row-major [out][in] = A-frag layout)
__global__ void prep_kernel(const float* __restrict__ conv_w, const float* __restrict__ lin_w,
                            unsigned short* __restrict__ cw16, unsigned short* __restrict__ lw16) {
  const int i = blockIdx.x * 256 + threadIdx.x;
  if (i < 128 * 256) cw16[i] = f2bf(conv_w[i]);
  if (i < 128 * 128) lw16[i] = f2bf(lin_w[i]);
}

// ---------------- conv1 (MFMA): yt[q][co] = sum_ci W[co][ci]*relu(x[ci][q])  (raw, no bias)
// Also accumulates per-co stats (sum, sumsq of raw acc over all q).
__global__ __launch_bounds__(256, 4) void conv1_mfma_kernel(
    const float* __restrict__ x, const unsigned short* __restrict__ cw16,
    unsigned short* __restrict__ yt, float* __restrict__ stats) {
  __shared__ __align__(16) unsigned short xT[64 * 32];   // [q_local][ci_local] bf16
  __shared__ float sredw[4][128];
  __shared__ float s2redw[4][128];
  const int t = threadIdx.x;
  const int w = t >> 6;
  const int l = t & 63;
  const int lr = l & 15;
  const int lg = l >> 4;
  const int q0 = blockIdx.x * 64;

  f32x4 acc[8];
#pragma unroll
  for (int tile = 0; tile < 8; tile++) acc[tile] = (f32x4){0.f, 0.f, 0.f, 0.f};

  // staging column base: q is 4-aligned and HW%4==0, so a float4 never crosses a batch
  const int qcol = q0 + 4 * (t & 15);
  const int bb = qcol / HW;
  const int pp = qcol - bb * HW;
  const float* xcol = x + (size_t)bb * CIN * HW + pp;

  for (int ch = 0; ch < 8; ch++) {
    __syncthreads();   // previous chunk's reads done
#pragma unroll
    for (int r = 0; r < 2; r++) {
      const int cil = (t >> 4) + r * 16;                     // 0..31
      float4 v = *(const float4*)&xcol[(size_t)(ch * 32 + cil) * HW];
      unsigned short* dst = &xT[(4 * (t & 15)) * 32 + cil];
      dst[0]  = f2bf(fmaxf(v.x, 0.f));
      dst[32] = f2bf(fmaxf(v.y, 0.f));
      dst[64] = f2bf(fmaxf(v.z, 0.f));
      dst[96] = f2bf(fmaxf(v.w, 0.f));
    }
    __syncthreads();   // writes visible
    bf16x8 bv = *(const bf16x8*)&xT[(w * 16 + lr) * 32 + lg * 8];
#pragma unroll
    for (int tile = 0; tile < 8; tile++) {
      bf16x8 av = *(const bf16x8*)&cw16[(size_t)(tile * 16 + lr) * 256 + ch * 32 + lg * 8];
      acc[tile] = __builtin_amdgcn_mfma_f32_16x16x32_bf16(av, bv, acc[tile], 0, 0, 0);
    }
  }

  // stats: reduce each (co) over the 16 cols held by the lr-group
#pragma unroll
  for (int tile = 0; tile < 8; tile++) {
#pragma unroll
    for (int i = 0; i < 4; i++) {
      float v = acc[tile][i];
      float v2 = v * v;
      v += __shfl_xor(v, 1); v2 += __shfl_xor(v2, 1);
      v += __shfl_xor(v, 2); v2 += __shfl_xor(v2, 2);
      v += __shfl_xor(v, 4); v2 += __shfl_xor(v2, 4);
      v += __shfl_xor(v, 8); v2 += __shfl_xor(v2, 8);
      if (lr == 0) {
        sredw[w][tile * 16 + lg * 4 + i] = v;
        s2redw[w][tile * 16 + lg * 4 + i] = v2;
      }
    }
  }

  // store yt (bf16, transposed [q][co] = conv2's B-frag layout)
  const int q = q0 + w * 16 + lr;
#pragma unroll
  for (int tile = 0; tile < 8; tile++) {
    union { unsigned short u[4]; uint2 v; } pk;
#pragma unroll
    for (int i = 0; i < 4; i++) pk.u[i] = f2bf(acc[tile][i]);
    *(uint2*)&yt[(size_t)q * 128 + tile * 16 + lg * 4] = pk.v;
  }

  __syncthreads();
  if (t < 128) {
    atomicAdd(&stats[t], sredw[0][t] + sredw[1][t] + sredw[2][t] + sredw[3][t]);
    atomicAdd(&stats[128 + t], s2redw[0][t] + s2redw[1][t] + s2redw[2][t] + s2redw[3][t]);
  }
}

// ---------------- BN fold (bias folded analytically; var invariant to bias shift):
// y = acc + cb; mean = E[acc]+cb; var = E[acc^2]-E[acc]^2
// BN(y) = y*s + t  ==  acc*s + (cb*s + t)
__global__ void scale_kernel(const float* __restrict__ stats, const float* __restrict__ conv_b,
                             const float* __restrict__ gamma, const float* __restrict__ beta,
                             float* __restrict__ sc) {
  const int c = threadIdx.x;
  const float inv_n = 1.f / (float)NQ;
  const float macc = stats[c] * inv_n;
  const float var = stats[128 + c] * inv_n - macc * macc;
  const float mean = macc + conv_b[c];
  const float s = gamma[c] * rsqrtf(var + 1e-5f);
  const float tt = beta[c] - mean * s;
  sc[c] = s;
  sc[128 + c] = conv_b[c] * s + tt;
}

// ---------------- conv2 (MFMA) + L2-normalize (with sqrt(1/T) folded) -> feat[q][o] bf16
__global__ __launch_bounds__(256, 4) void conv2_mfma_kernel(
    const unsigned short* __restrict__ yt, const unsigned short* __restrict__ lw16,
    const float* __restrict__ sc, const float* __restrict__ lin_b,
    unsigned short* __restrict__ feat) {
  const int t = threadIdx.x;
  const int w = t >> 6;
  const int l = t & 63;
  const int lr = l & 15;
  const int lg = l >> 4;
  const int q = blockIdx.x * 64 + w * 16 + lr;

  f32x4 acc[8];
#pragma unroll
  for (int tile = 0; tile < 8; tile++) acc[tile] = (f32x4){0.f, 0.f, 0.f, 0.f};

  const unsigned short* yrow = yt + (size_t)q * 128;
  for (int ch = 0; ch < 4; ch++) {
    bf16x8 raw = *(const bf16x8*)&yrow[ch * 32 + lg * 8];
    bf16x8 bv;
#pragma unroll
    for (int e = 0; e < 8; e++) {
      const int c = ch * 32 + lg * 8 + e;
      float v = fmaxf(fmaf(bf2f((unsigned short)raw[e]), sc[c], sc[128 + c]), 0.f);
      bv[e] = (short)f2bf(v);
    }
#pragma unroll
    for (int tile = 0; tile < 8; tile++) {
      bf16x8 av = *(const bf16x8*)&lw16[(size_t)(tile * 16 + lr) * 128 + ch * 32 + lg * 8];
      acc[tile] = __builtin_amdgcn_mfma_f32_16x16x32_bf16(av, bv, acc[tile], 0, 0, 0);
    }
  }

  float vals[8][4];
  float ssq = 0.f;
#pragma unroll
  for (int tile = 0; tile < 8; tile++) {
#pragma unroll
    for (int i = 0; i < 4; i++) {
      float v = acc[tile][i] + lin_b[tile * 16 + lg * 4 + i];
      vals[tile][i] = v;
      ssq += v * v;
    }
  }
  ssq += __shfl_xor(ssq, 16);   // across the 4 lane-groups holding the same column q
  ssq += __shfl_xor(ssq, 32);
  const float inv = SQRT_INV_T / fmaxf(sqrtf(ssq), 1e-12f);

#pragma unroll
  for (int tile = 0; tile < 8; tile++) {
    union { unsigned short u[4]; uint2 v; } pk;
#pragma unroll
    for (int i = 0; i < 4; i++) pk.u[i] = f2bf(vals[tile][i] * inv);
    *(uint2*)&feat[(size_t)q * 128 + tile * 16 + lg * 4] = pk.v;
  }
}

// ---------------- InfoNCE: wave owns 64 rows (A in regs), streams 48-col chunks.
// feats carry sqrt(1/T), so MFMA acc == logit. sumexp[r] += sum_c exp2(logit*log2e - M*log2e)
__global__ __launch_bounds__(256, 2) void infonce_kernel(
    const unsigned short* __restrict__ fo, const unsigned short* __restrict__ ft,
    float* __restrict__ sumexp) {
  const int b = blockIdx.z;
  const int t = threadIdx.x;
  const int w = t >> 6;
  const int lane = t & 63;
  const int lr = lane & 15;
  const int lkq = lane >> 4;            // 0..3
  const int base = blockIdx.x * 256 + w * 64;
  if (base >= HW) return;               // no barriers in kernel -> safe
  const unsigned short* fob = fo + (size_t)b * HW * 128;
  const unsigned short* ftb = ft + (size_t)b * HW * 128;

  bf16x8 a[4][4];                       // [tile][kk]
#pragma unroll
  for (int tile = 0; tile < 4; tile++) {
    const int r = min(base + tile * 16 + lr, HW - 1);
    const unsigned short* ap = fob + (size_t)r * 128 + lkq * 8;
#pragma unroll
    for (int kk = 0; kk < 4; kk++) a[tile][kk] = *(const bf16x8*)(ap + kk * 32);
  }
  float rs[4][4];
#pragma unroll
  for (int tile = 0; tile < 4; tile++)
#pragma unroll
    for (int i = 0; i < 4; i++) rs[tile][i] = 0.f;

  for (int ch = blockIdx.y; ch < 75; ch += 4) {
    const int cbase = ch * 48;
    bf16x8 bv[3][4];
#pragma unroll
    for (int sub = 0; sub < 3; sub++) {
      const unsigned short* bp = ftb + (size_t)(cbase + sub * 16 + lr) * 128 + lkq * 8;
#pragma unroll
      for (int kk = 0; kk < 4; kk++) bv[sub][kk] = *(const bf16x8*)(bp + kk * 32);
    }
    f32x4 acc[4][3];
#pragma unroll
    for (int tile = 0; tile < 4; tile++)
#pragma unroll
      for (int sub = 0; sub < 3; sub++) acc[tile][sub] = (f32x4){0.f, 0.f, 0.f, 0.f};
#pragma unroll
    for (int kk = 0; kk < 4; kk++)
#pragma unroll
      for (int tile = 0; tile < 4; tile++)
#pragma unroll
        for (int sub = 0; sub < 3; sub++)
          acc[tile][sub] = __builtin_amdgcn_mfma_f32_16x16x32_bf16(
              a[tile][kk], bv[sub][kk], acc[tile][sub], 0, 0, 0);
#pragma unroll
    for (int tile = 0; tile < 4; tile++)
#pragma unroll
      for (int sub = 0; sub < 3; sub++)
#pragma unroll
        for (int i = 0; i < 4; i++)
          rs[tile][i] += exp2f(fmaf(acc[tile][sub][i], LOG2E, NM));
  }
  // reduce col-partials over lr (within each 16-lane group)
#pragma unroll
  for (int tile = 0; tile < 4; tile++)
#pragma unroll
    for (int i = 0; i < 4; i++) {
      float v = rs[tile][i];
      v += __shfl_xor(v, 1); v += __shfl_xor(v, 2);
      v += __shfl_xor(v, 4); v += __shfl_xor(v, 8);
      rs[tile][i] = v;
    }
  if (lr == 0) {
#pragma unroll
    for (int tile = 0; tile < 4; tile++)
#pragma unroll
      for (int i = 0; i < 4; i++) {
        const int r = base + tile * 16 + lkq * 4 + i;
        if (r < HW) atomicAdd(&sumexp[b * HW + r], rs[tile][i]);
      }
  }
}

// ---------------- final: mean over q of (log(sumexp)+1/T - dot')   [dot' already /T]
__global__ __launch_bounds__(256) void final_kernel(
    const float* __restrict__ sumexp, const unsigned short* __restrict__ fo,
    const unsigned short* __restrict__ ft, float* __restrict__ out) {
  const int q = blockIdx.x * 256 + threadIdx.x;
  float val = 0.f;
  if (q < NQ) {
    const unsigned short* a = fo + (size_t)q * 128;
    const unsigned short* c = ft + (size_t)q * 128;
    float dot = 0.f;
#pragma unroll
    for (int k = 0; k < 128; k += 8) {
      bf16x8 ua = *(const bf16x8*)(a + k);
      bf16x8 ub = *(const bf16x8*)(c + k);
#pragma unroll
      for (int e = 0; e < 8; e++)
        dot = fmaf(bf2f((unsigned short)ua[e]), bf2f((unsigned short)ub[e]), dot);
    }
    val = logf(sumexp[q]) + INV_T - dot;
  }
#pragma unroll
  for (int m = 1; m < 64; m <<= 1) val += __shfl_xor(val, m);
  __shared__ float red[4];
  const int wid = threadIdx.x >> 6;
  if ((threadIdx.x & 63) == 0) red[wid] = val;
  __syncthreads();
  if (threadIdx.x == 0)
    atomicAdd(out, (red[0] + red[1] + red[2] + red[3]) * (1.f / (float)NQ));
}

extern "C" void kernel_launch(void* const* d_in, const int* in_sizes, int n_in,
                              void* d_out, int out_size, void* d_ws, size_t ws_size,
                              hipStream_t stream) {
  (void)in_sizes; (void)n_in; (void)out_size; (void)ws_size;
  const float* x_orig = (const float*)d_in[0];
  const float* x_trans = (const float*)d_in[1];
  const float* conv_w = (const float*)d_in[2];
  const float* conv_b = (const float*)d_in[3];
  const float* gamma = (const float*)d_in[4];
  const float* beta = (const float*)d_in[5];
  const float* lin_w = (const float*)d_in[6];
  const float* lin_b = (const float*)d_in[7];
  float* out = (float*)d_out;

  char* ws = (char*)d_ws;
  unsigned short* yt = (unsigned short*)(ws + 0);            //  7,372,800 B
  unsigned short* cw16 = (unsigned short*)(ws + 7372800);    //     65,536 B
  unsigned short* lw16 = (unsigned short*)(ws + 7438336);    //     32,768 B
  float* statsO = (float*)(ws + 7471104);                    //      1,024 B
  float* statsT = (float*)(ws + 7472128);                    //      1,024 B
  float* scO = (float*)(ws + 7473152);                       //      1,024 B
  float* scT = (float*)(ws + 7474176);                       //      1,024 B
  float* sumexp = (float*)(ws + 7475200);                    //    115,200 B
  unsigned short* feat_o = (unsigned short*)(ws + 7590400);  //  7,372,800 B
  unsigned short* feat_t = (unsigned short*)(ws + 14963200); //  7,372,800 B

  hipMemsetAsync(ws + 7471104, 0, 2048 + 2048 + 115200, stream);  // stats+sc+sumexp
  hipMemsetAsync(d_out, 0, sizeof(float), stream);

  prep_kernel<<<128, 256, 0, stream>>>(conv_w, lin_w, cw16, lw16);

  conv1_mfma_kernel<<<450, 256, 0, stream>>>(x_orig, cw16, yt, statsO);
  scale_kernel<<<1, 128, 0, stream>>>(statsO, conv_b, gamma, beta, scO);
  conv2_mfma_kernel<<<450, 256, 0, stream>>>(yt, lw16, scO, lin_b, feat_o);

  conv1_mfma_kernel<<<450, 256, 0, stream>>>(x_trans, cw16, yt, statsT);
  scale_kernel<<<1, 128, 0, stream>>>(statsT, conv_b, gamma, beta, scT);
  conv2_mfma_kernel<<<450, 256, 0, stream>>>(yt, lw16, scT, lin_b, feat_t);

  infonce_kernel<<<dim3(15, 4, 8), 256, 0, stream>>>(feat_o, feat_t, sumexp);
  final_kernel<<<113, 256, 0, stream>>>(sumexp, feat_o, feat_t, out);
}

// Round 4
// 258.921 us; speedup vs baseline: 1.7191x; 1.0762x over previous
//
#include <hip/hip_runtime.h>
#include <hip/hip_bf16.h>

#define HW 3600
#define NQ 28800
#define CIN 256
#define CMID 128

typedef short bf16x8 __attribute__((ext_vector_type(8)));
typedef float f32x4 __attribute__((ext_vector_type(4)));

#define INV_T 14.285714285714286f
#define SQRT_INV_T 3.7796447300922722f
#define LOG2E 1.4426950408889634f
#define NM (-20.60992915555662f)   /* -INV_T*LOG2E */

__device__ inline unsigned short f2bf(float f) {
  unsigned u = __float_as_uint(f);
  return (unsigned short)((u + 0x7fffu + ((u >> 16) & 1u)) >> 16);  // RNE
}
__device__ inline float bf2f(unsigned short h) { return __uint_as_float((unsigned)h << 16); }

// ---------------- prep: fp32 weights -> bf16 (native row-major [out][in] = A-frag layout)
__global__ void prep_kernel(const float* __restrict__ conv_w, const float* __restrict__ lin_w,
                            unsigned short* __restrict__ cw16, unsigned short* __restrict__ lw16) {
  const int i = blockIdx.x * 256 + threadIdx.x;
  if (i < 128 * 256) cw16[i] = f2bf(conv_w[i]);
  if (i < 128 * 128) lw16[i] = f2bf(lin_w[i]);
}

// ---------------- conv1 (MFMA), both branches in one launch (blockIdx.z):
// yt[z][q][co] = sum_ci W[co][ci]*relu(x_z[ci][q])  (raw, no bias), + per-co stats.
__global__ __launch_bounds__(256, 4) void conv1_mfma_kernel(
    const float* __restrict__ x0, const float* __restrict__ x1,
    const unsigned short* __restrict__ cw16,
    unsigned short* __restrict__ yt, float* __restrict__ stats) {
  __shared__ __align__(16) unsigned short xT[64 * 32];   // [q_local][ci_local] bf16
  __shared__ float sredw[4][128];
  __shared__ float s2redw[4][128];
  const int z = blockIdx.z;
  const float* x = z ? x1 : x0;
  float* st = stats + z * 256;
  unsigned short* yz = yt + (size_t)z * NQ * 128;

  const int t = threadIdx.x;
  const int w = t >> 6;
  const int l = t & 63;
  const int lr = l & 15;
  const int lg = l >> 4;
  const int q0 = blockIdx.x * 64;

  f32x4 acc[8];
#pragma unroll
  for (int tile = 0; tile < 8; tile++) acc[tile] = (f32x4){0.f, 0.f, 0.f, 0.f};

  // staging column base: q is 4-aligned and HW%4==0, so a float4 never crosses a batch
  const int qcol = q0 + 4 * (t & 15);
  const int bb = qcol / HW;
  const int pp = qcol - bb * HW;
  const float* xcol = x + (size_t)bb * CIN * HW + pp;
  const int cil0 = (t >> 4);
  const int cil1 = cil0 + 16;

  float4 v0 = *(const float4*)&xcol[(size_t)cil0 * HW];
  float4 v1 = *(const float4*)&xcol[(size_t)cil1 * HW];

  for (int ch = 0; ch < 8; ch++) {
    if (ch) __syncthreads();   // previous chunk's LDS reads done
    {
      unsigned short* dst = &xT[(4 * (t & 15)) * 32 + cil0];
      dst[0]  = f2bf(fmaxf(v0.x, 0.f));
      dst[32] = f2bf(fmaxf(v0.y, 0.f));
      dst[64] = f2bf(fmaxf(v0.z, 0.f));
      dst[96] = f2bf(fmaxf(v0.w, 0.f));
      dst = &xT[(4 * (t & 15)) * 32 + cil1];
      dst[0]  = f2bf(fmaxf(v1.x, 0.f));
      dst[32] = f2bf(fmaxf(v1.y, 0.f));
      dst[64] = f2bf(fmaxf(v1.z, 0.f));
      dst[96] = f2bf(fmaxf(v1.w, 0.f));
    }
    __syncthreads();           // writes visible
    if (ch < 7) {              // prefetch next chunk (overlaps MFMAs below)
      v0 = *(const float4*)&xcol[(size_t)((ch + 1) * 32 + cil0) * HW];
      v1 = *(const float4*)&xcol[(size_t)((ch + 1) * 32 + cil1) * HW];
    }
    bf16x8 bv = *(const bf16x8*)&xT[(w * 16 + lr) * 32 + lg * 8];
#pragma unroll
    for (int tile = 0; tile < 8; tile++) {
      bf16x8 av = *(const bf16x8*)&cw16[(size_t)(tile * 16 + lr) * 256 + ch * 32 + lg * 8];
      acc[tile] = __builtin_amdgcn_mfma_f32_16x16x32_bf16(av, bv, acc[tile], 0, 0, 0);
    }
  }

  // stats: reduce each (co) over the 16 cols held by the lr-group
#pragma unroll
  for (int tile = 0; tile < 8; tile++) {
#pragma unroll
    for (int i = 0; i < 4; i++) {
      float v = acc[tile][i];
      float v2 = v * v;
      v += __shfl_xor(v, 1); v2 += __shfl_xor(v2, 1);
      v += __shfl_xor(v, 2); v2 += __shfl_xor(v2, 2);
      v += __shfl_xor(v, 4); v2 += __shfl_xor(v2, 4);
      v += __shfl_xor(v, 8); v2 += __shfl_xor(v2, 8);
      if (lr == 0) {
        sredw[w][tile * 16 + lg * 4 + i] = v;
        s2redw[w][tile * 16 + lg * 4 + i] = v2;
      }
    }
  }

  // store yt (bf16, transposed [q][co] = conv2's B-frag layout)
  const int q = q0 + w * 16 + lr;
#pragma unroll
  for (int tile = 0; tile < 8; tile++) {
    union { unsigned short u[4]; uint2 v; } pk;
#pragma unroll
    for (int i = 0; i < 4; i++) pk.u[i] = f2bf(acc[tile][i]);
    *(uint2*)&yz[(size_t)q * 128 + tile * 16 + lg * 4] = pk.v;
  }

  __syncthreads();
  if (t < 128) {
    atomicAdd(&st[t], sredw[0][t] + sredw[1][t] + sredw[2][t] + sredw[3][t]);
    atomicAdd(&st[128 + t], s2redw[0][t] + s2redw[1][t] + s2redw[2][t] + s2redw[3][t]);
  }
}

// ---------------- BN fold, both branches (blockIdx.x = z):
// y = acc + cb; mean = E[acc]+cb; var = E[acc^2]-E[acc]^2;  BN(y) = acc*s + (cb*s + t)
__global__ void scale_kernel(const float* __restrict__ stats, const float* __restrict__ conv_b,
                             const float* __restrict__ gamma, const float* __restrict__ beta,
                             float* __restrict__ sc) {
  const int z = blockIdx.x;
  const float* st = stats + z * 256;
  float* scz = sc + z * 256;
  const int c = threadIdx.x;
  const float inv_n = 1.f / (float)NQ;
  const float macc = st[c] * inv_n;
  const float var = st[128 + c] * inv_n - macc * macc;
  const float mean = macc + conv_b[c];
  const float s = gamma[c] * rsqrtf(var + 1e-5f);
  const float tt = beta[c] - mean * s;
  scz[c] = s;
  scz[128 + c] = conv_b[c] * s + tt;
}

// ---------------- conv2 (MFMA) + L2-normalize (sqrt(1/T) folded), both branches
__global__ __launch_bounds__(256, 4) void conv2_mfma_kernel(
    const unsigned short* __restrict__ yt, const unsigned short* __restrict__ lw16,
    const float* __restrict__ sc, const float* __restrict__ lin_b,
    unsigned short* __restrict__ feat_o, unsigned short* __restrict__ feat_t) {
  const int z = blockIdx.z;
  const unsigned short* yz = yt + (size_t)z * NQ * 128;
  const float* scz = sc + z * 256;
  unsigned short* feat = z ? feat_t : feat_o;

  const int t = threadIdx.x;
  const int w = t >> 6;
  const int l = t & 63;
  const int lr = l & 15;
  const int lg = l >> 4;
  const int q = blockIdx.x * 64 + w * 16 + lr;

  f32x4 acc[8];
#pragma unroll
  for (int tile = 0; tile < 8; tile++) acc[tile] = (f32x4){0.f, 0.f, 0.f, 0.f};

  const unsigned short* yrow = yz + (size_t)q * 128;
  for (int ch = 0; ch < 4; ch++) {
    bf16x8 raw = *(const bf16x8*)&yrow[ch * 32 + lg * 8];
    bf16x8 bv;
#pragma unroll
    for (int e = 0; e < 8; e++) {
      const int c = ch * 32 + lg * 8 + e;
      float v = fmaxf(fmaf(bf2f((unsigned short)raw[e]), scz[c], scz[128 + c]), 0.f);
      bv[e] = (short)f2bf(v);
    }
#pragma unroll
    for (int tile = 0; tile < 8; tile++) {
      bf16x8 av = *(const bf16x8*)&lw16[(size_t)(tile * 16 + lr) * 128 + ch * 32 + lg * 8];
      acc[tile] = __builtin_amdgcn_mfma_f32_16x16x32_bf16(av, bv, acc[tile], 0, 0, 0);
    }
  }

  float vals[8][4];
  float ssq = 0.f;
#pragma unroll
  for (int tile = 0; tile < 8; tile++) {
#pragma unroll
    for (int i = 0; i < 4; i++) {
      float v = acc[tile][i] + lin_b[tile * 16 + lg * 4 + i];
      vals[tile][i] = v;
      ssq += v * v;
    }
  }
  ssq += __shfl_xor(ssq, 16);   // across the 4 lane-groups holding the same column q
  ssq += __shfl_xor(ssq, 32);
  const float inv = SQRT_INV_T / fmaxf(sqrtf(ssq), 1e-12f);

#pragma unroll
  for (int tile = 0; tile < 8; tile++) {
    union { unsigned short u[4]; uint2 v; } pk;
#pragma unroll
    for (int i = 0; i < 4; i++) pk.u[i] = f2bf(vals[tile][i] * inv);
    *(uint2*)&feat[(size_t)q * 128 + tile * 16 + lg * 4] = pk.v;
  }
}

// ---------------- InfoNCE: wave owns 64 rows (A in regs), streams 48-col chunks.
// feats carry sqrt(1/T), so MFMA acc == logit. sumexp[r] += sum_c exp2(logit*log2e - M*log2e)
__global__ __launch_bounds__(256, 2) void infonce_kernel(
    const unsigned short* __restrict__ fo, const unsigned short* __restrict__ ft,
    float* __restrict__ sumexp) {
  const int b = blockIdx.z;
  const int t = threadIdx.x;
  const int w = t >> 6;
  const int lane = t & 63;
  const int lr = lane & 15;
  const int lkq = lane >> 4;            // 0..3
  const int base = blockIdx.x * 256 + w * 64;
  if (base >= HW) return;               // no barriers in kernel -> safe
  const unsigned short* fob = fo + (size_t)b * HW * 128;
  const unsigned short* ftb = ft + (size_t)b * HW * 128;

  bf16x8 a[4][4];                       // [tile][kk]
#pragma unroll
  for (int tile = 0; tile < 4; tile++) {
    const int r = min(base + tile * 16 + lr, HW - 1);
    const unsigned short* ap = fob + (size_t)r * 128 + lkq * 8;
#pragma unroll
    for (int kk = 0; kk < 4; kk++) a[tile][kk] = *(const bf16x8*)(ap + kk * 32);
  }
  float rs[4][4];
#pragma unroll
  for (int tile = 0; tile < 4; tile++)
#pragma unroll
    for (int i = 0; i < 4; i++) rs[tile][i] = 0.f;

  for (int ch = blockIdx.y; ch < 75; ch += 15) {
    const int cbase = ch * 48;
    bf16x8 bv[3][4];
#pragma unroll
    for (int sub = 0; sub < 3; sub++) {
      const unsigned short* bp = ftb + (size_t)(cbase + sub * 16 + lr) * 128 + lkq * 8;
#pragma unroll
      for (int kk = 0; kk < 4; kk++) bv[sub][kk] = *(const bf16x8*)(bp + kk * 32);
    }
    f32x4 acc[4][3];
#pragma unroll
    for (int tile = 0; tile < 4; tile++)
#pragma unroll
      for (int sub = 0; sub < 3; sub++) acc[tile][sub] = (f32x4){0.f, 0.f, 0.f, 0.f};
#pragma unroll
    for (int kk = 0; kk < 4; kk++)
#pragma unroll
      for (int tile = 0; tile < 4; tile++)
#pragma unroll
        for (int sub = 0; sub < 3; sub++)
          acc[tile][sub] = __builtin_amdgcn_mfma_f32_16x16x32_bf16(
              a[tile][kk], bv[sub][kk], acc[tile][sub], 0, 0, 0);
#pragma unroll
    for (int tile = 0; tile < 4; tile++)
#pragma unroll
      for (int sub = 0; sub < 3; sub++)
#pragma unroll
        for (int i = 0; i < 4; i++)
          rs[tile][i] += exp2f(fmaf(acc[tile][sub][i], LOG2E, NM));
  }
  // reduce col-partials over lr (within each 16-lane group)
#pragma unroll
  for (int tile = 0; tile < 4; tile++)
#pragma unroll
    for (int i = 0; i < 4; i++) {
      float v = rs[tile][i];
      v += __shfl_xor(v, 1); v += __shfl_xor(v, 2);
      v += __shfl_xor(v, 4); v += __shfl_xor(v, 8);
      rs[tile][i] = v;
    }
  if (lr == 0) {
#pragma unroll
    for (int tile = 0; tile < 4; tile++)
#pragma unroll
      for (int i = 0; i < 4; i++) {
        const int r = base + tile * 16 + lkq * 4 + i;
        if (r < HW) atomicAdd(&sumexp[b * HW + r], rs[tile][i]);
      }
  }
}

// ---------------- final: mean over q of (log(sumexp)+1/T - dot')   [dot' already /T]
__global__ __launch_bounds__(256) void final_kernel(
    const float* __restrict__ sumexp, const unsigned short* __restrict__ fo,
    const unsigned short* __restrict__ ft, float* __restrict__ out) {
  const int q = blockIdx.x * 256 + threadIdx.x;
  float val = 0.f;
  if (q < NQ) {
    const unsigned short* a = fo + (size_t)q * 128;
    const unsigned short* c = ft + (size_t)q * 128;
    float dot = 0.f;
#pragma unroll
    for (int k = 0; k < 128; k += 8) {
      bf16x8 ua = *(const bf16x8*)(a + k);
      bf16x8 ub = *(const bf16x8*)(c + k);
#pragma unroll
      for (int e = 0; e < 8; e++)
        dot = fmaf(bf2f((unsigned short)ua[e]), bf2f((unsigned short)ub[e]), dot);
    }
    val = logf(sumexp[q]) + INV_T - dot;
  }
#pragma unroll
  for (int m = 1; m < 64; m <<= 1) val += __shfl_xor(val, m);
  __shared__ float red[4];
  const int wid = threadIdx.x >> 6;
  if ((threadIdx.x & 63) == 0) red[wid] = val;
  __syncthreads();
  if (threadIdx.x == 0)
    atomicAdd(out, (red[0] + red[1] + red[2] + red[3]) * (1.f / (float)NQ));
}

extern "C" void kernel_launch(void* const* d_in, const int* in_sizes, int n_in,
                              void* d_out, int out_size, void* d_ws, size_t ws_size,
                              hipStream_t stream) {
  (void)in_sizes; (void)n_in; (void)out_size; (void)ws_size;
  const float* x_orig = (const float*)d_in[0];
  const float* x_trans = (const float*)d_in[1];
  const float* conv_w = (const float*)d_in[2];
  const float* conv_b = (const float*)d_in[3];
  const float* gamma = (const float*)d_in[4];
  const float* beta = (const float*)d_in[5];
  const float* lin_w = (const float*)d_in[6];
  const float* lin_b = (const float*)d_in[7];
  float* out = (float*)d_out;

  char* ws = (char*)d_ws;
  unsigned short* yt = (unsigned short*)(ws + 0);            // 2 x 7,372,800 B
  unsigned short* cw16 = (unsigned short*)(ws + 14745600);   //     65,536 B
  unsigned short* lw16 = (unsigned short*)(ws + 14811136);   //     32,768 B
  float* stats = (float*)(ws + 14843904);                    //  2 x 1,024 B
  float* sc = (float*)(ws + 14845952);                       //  2 x 1,024 B
  float* sumexp = (float*)(ws + 14848000);                   //    115,200 B
  unsigned short* feat_o = (unsigned short*)(ws + 14963200); //  7,372,800 B
  unsigned short* feat_t = (unsigned short*)(ws + 22336000); //  7,372,800 B
  // end: 29,708,800 B

  hipMemsetAsync(ws + 14843904, 0, 2048 + 2048 + 115200, stream);  // stats+sc+sumexp
  hipMemsetAsync(d_out, 0, sizeof(float), stream);

  prep_kernel<<<128, 256, 0, stream>>>(conv_w, lin_w, cw16, lw16);

  conv1_mfma_kernel<<<dim3(450, 1, 2), 256, 0, stream>>>(x_orig, x_trans, cw16, yt, stats);
  scale_kernel<<<2, 128, 0, stream>>>(stats, conv_b, gamma, beta, sc);
  conv2_mfma_kernel<<<dim3(450, 1, 2), 256, 0, stream>>>(yt, lw16, sc, lin_b, feat_o, feat_t);

  infonce_kernel<<<dim3(15, 15, 8), 256, 0, stream>>>(feat_o, feat_t, sumexp);
  final_kernel<<<113, 256, 0, stream>>>(sumexp, feat_o, feat_t, out);
}

// Round 5
// 250.123 us; speedup vs baseline: 1.7796x; 1.0352x over previous
//
#include <hip/hip_runtime.h>
#include <hip/hip_bf16.h>

#define HW 3600
#define NQ 28800
#define CIN 256
#define CMID 128
#define NSHARD 16

typedef short bf16x8 __attribute__((ext_vector_type(8)));
typedef float f32x4 __attribute__((ext_vector_type(4)));

#define INV_T 14.285714285714286f
#define SQRT_INV_T 3.7796447300922722f
#define LOG2E 1.4426950408889634f
#define NM (-20.60992915555662f)   /* -INV_T*LOG2E */

__device__ inline unsigned short f2bf(float f) {
  unsigned u = __float_as_uint(f);
  return (unsigned short)((u + 0x7fffu + ((u >> 16) & 1u)) >> 16);  // RNE
}
__device__ inline float bf2f(unsigned short h) { return __uint_as_float((unsigned)h << 16); }

// ---------------- prep: fp32 weights -> bf16 (native row-major [out][in] = A-frag layout)
__global__ void prep_kernel(const float* __restrict__ conv_w, const float* __restrict__ lin_w,
                            unsigned short* __restrict__ cw16, unsigned short* __restrict__ lw16) {
  const int i = blockIdx.x * 256 + threadIdx.x;
  if (i < 128 * 256) cw16[i] = f2bf(conv_w[i]);
  if (i < 128 * 128) lw16[i] = f2bf(lin_w[i]);
}

// ---------------- conv1 (MFMA), both branches in one launch (blockIdx.z):
// yt[z][q][co] = sum_ci W[co][ci]*relu(x_z[ci][q])  (raw, no bias), + sharded per-co stats.
__global__ __launch_bounds__(256, 4) void conv1_mfma_kernel(
    const float* __restrict__ x0, const float* __restrict__ x1,
    const unsigned short* __restrict__ cw16,
    unsigned short* __restrict__ yt, float* __restrict__ stats) {
  __shared__ __align__(16) unsigned short xT[64 * 32];   // [q_local][ci_local] bf16
  __shared__ float sredw[4][128];
  __shared__ float s2redw[4][128];
  const int z = blockIdx.z;
  const float* x = z ? x1 : x0;
  float* st = stats + (z * NSHARD + (blockIdx.x & (NSHARD - 1))) * 256;
  unsigned short* yz = yt + (size_t)z * NQ * 128;

  const int t = threadIdx.x;
  const int w = t >> 6;
  const int l = t & 63;
  const int lr = l & 15;
  const int lg = l >> 4;
  const int q0 = blockIdx.x * 64;

  f32x4 acc[8];
#pragma unroll
  for (int tile = 0; tile < 8; tile++) acc[tile] = (f32x4){0.f, 0.f, 0.f, 0.f};

  // staging column base: q is 4-aligned and HW%4==0, so a float4 never crosses a batch
  const int qcol = q0 + 4 * (t & 15);
  const int bb = qcol / HW;
  const int pp = qcol - bb * HW;
  const float* xcol = x + (size_t)bb * CIN * HW + pp;
  const int cil0 = (t >> 4);
  const int cil1 = cil0 + 16;

  float4 v0 = *(const float4*)&xcol[(size_t)cil0 * HW];
  float4 v1 = *(const float4*)&xcol[(size_t)cil1 * HW];

  for (int ch = 0; ch < 8; ch++) {
    if (ch) __syncthreads();   // previous chunk's LDS reads done
    {
      unsigned short* dst = &xT[(4 * (t & 15)) * 32 + cil0];
      dst[0]  = f2bf(fmaxf(v0.x, 0.f));
      dst[32] = f2bf(fmaxf(v0.y, 0.f));
      dst[64] = f2bf(fmaxf(v0.z, 0.f));
      dst[96] = f2bf(fmaxf(v0.w, 0.f));
      dst = &xT[(4 * (t & 15)) * 32 + cil1];
      dst[0]  = f2bf(fmaxf(v1.x, 0.f));
      dst[32] = f2bf(fmaxf(v1.y, 0.f));
      dst[64] = f2bf(fmaxf(v1.z, 0.f));
      dst[96] = f2bf(fmaxf(v1.w, 0.f));
    }
    __syncthreads();           // writes visible
    if (ch < 7) {              // prefetch next chunk (overlaps MFMAs below)
      v0 = *(const float4*)&xcol[(size_t)((ch + 1) * 32 + cil0) * HW];
      v1 = *(const float4*)&xcol[(size_t)((ch + 1) * 32 + cil1) * HW];
    }
    bf16x8 bv = *(const bf16x8*)&xT[(w * 16 + lr) * 32 + lg * 8];
#pragma unroll
    for (int tile = 0; tile < 8; tile++) {
      bf16x8 av = *(const bf16x8*)&cw16[(size_t)(tile * 16 + lr) * 256 + ch * 32 + lg * 8];
      acc[tile] = __builtin_amdgcn_mfma_f32_16x16x32_bf16(av, bv, acc[tile], 0, 0, 0);
    }
  }

  // stats: reduce each (co) over the 16 cols held by the lr-group
#pragma unroll
  for (int tile = 0; tile < 8; tile++) {
#pragma unroll
    for (int i = 0; i < 4; i++) {
      float v = acc[tile][i];
      float v2 = v * v;
      v += __shfl_xor(v, 1); v2 += __shfl_xor(v2, 1);
      v += __shfl_xor(v, 2); v2 += __shfl_xor(v2, 2);
      v += __shfl_xor(v, 4); v2 += __shfl_xor(v2, 4);
      v += __shfl_xor(v, 8); v2 += __shfl_xor(v2, 8);
      if (lr == 0) {
        sredw[w][tile * 16 + lg * 4 + i] = v;
        s2redw[w][tile * 16 + lg * 4 + i] = v2;
      }
    }
  }

  // store yt (bf16, transposed [q][co] = conv2's B-frag layout)
  const int q = q0 + w * 16 + lr;
#pragma unroll
  for (int tile = 0; tile < 8; tile++) {
    union { unsigned short u[4]; uint2 v; } pk;
#pragma unroll
    for (int i = 0; i < 4; i++) pk.u[i] = f2bf(acc[tile][i]);
    *(uint2*)&yz[(size_t)q * 128 + tile * 16 + lg * 4] = pk.v;
  }

  __syncthreads();
  if (t < 128) {
    atomicAdd(&st[t], sredw[0][t] + sredw[1][t] + sredw[2][t] + sredw[3][t]);
    atomicAdd(&st[128 + t], s2redw[0][t] + s2redw[1][t] + s2redw[2][t] + s2redw[3][t]);
  }
}

// ---------------- BN fold, both branches (blockIdx.x = z), summing shards:
// y = acc + cb; mean = E[acc]+cb; var = E[acc^2]-E[acc]^2;  BN(y) = acc*s + (cb*s + t)
__global__ void scale_kernel(const float* __restrict__ stats, const float* __restrict__ conv_b,
                             const float* __restrict__ gamma, const float* __restrict__ beta,
                             float* __restrict__ sc) {
  const int z = blockIdx.x;
  const float* st = stats + z * NSHARD * 256;
  float* scz = sc + z * 256;
  const int c = threadIdx.x;
  float s1 = 0.f, s2 = 0.f;
#pragma unroll
  for (int sh = 0; sh < NSHARD; sh++) {
    s1 += st[sh * 256 + c];
    s2 += st[sh * 256 + 128 + c];
  }
  const float inv_n = 1.f / (float)NQ;
  const float macc = s1 * inv_n;
  const float var = s2 * inv_n - macc * macc;
  const float mean = macc + conv_b[c];
  const float s = gamma[c] * rsqrtf(var + 1e-5f);
  const float tt = beta[c] - mean * s;
  scz[c] = s;
  scz[128 + c] = conv_b[c] * s + tt;
}

// ---------------- conv2 (MFMA) + L2-normalize (sqrt(1/T) folded), both branches
__global__ __launch_bounds__(256, 4) void conv2_mfma_kernel(
    const unsigned short* __restrict__ yt, const unsigned short* __restrict__ lw16,
    const float* __restrict__ sc, const float* __restrict__ lin_b,
    unsigned short* __restrict__ feat_o, unsigned short* __restrict__ feat_t) {
  const int z = blockIdx.z;
  const unsigned short* yz = yt + (size_t)z * NQ * 128;
  const float* scz = sc + z * 256;
  unsigned short* feat = z ? feat_t : feat_o;

  const int t = threadIdx.x;
  const int w = t >> 6;
  const int l = t & 63;
  const int lr = l & 15;
  const int lg = l >> 4;
  const int q = blockIdx.x * 64 + w * 16 + lr;

  f32x4 acc[8];
#pragma unroll
  for (int tile = 0; tile < 8; tile++) acc[tile] = (f32x4){0.f, 0.f, 0.f, 0.f};

  const unsigned short* yrow = yz + (size_t)q * 128;
  for (int ch = 0; ch < 4; ch++) {
    bf16x8 raw = *(const bf16x8*)&yrow[ch * 32 + lg * 8];
    bf16x8 bv;
#pragma unroll
    for (int e = 0; e < 8; e++) {
      const int c = ch * 32 + lg * 8 + e;
      float v = fmaxf(fmaf(bf2f((unsigned short)raw[e]), scz[c], scz[128 + c]), 0.f);
      bv[e] = (short)f2bf(v);
    }
#pragma unroll
    for (int tile = 0; tile < 8; tile++) {
      bf16x8 av = *(const bf16x8*)&lw16[(size_t)(tile * 16 + lr) * 128 + ch * 32 + lg * 8];
      acc[tile] = __builtin_amdgcn_mfma_f32_16x16x32_bf16(av, bv, acc[tile], 0, 0, 0);
    }
  }

  float vals[8][4];
  float ssq = 0.f;
#pragma unroll
  for (int tile = 0; tile < 8; tile++) {
#pragma unroll
    for (int i = 0; i < 4; i++) {
      float v = acc[tile][i] + lin_b[tile * 16 + lg * 4 + i];
      vals[tile][i] = v;
      ssq += v * v;
    }
  }
  ssq += __shfl_xor(ssq, 16);   // across the 4 lane-groups holding the same column q
  ssq += __shfl_xor(ssq, 32);
  const float inv = SQRT_INV_T / fmaxf(sqrtf(ssq), 1e-12f);

#pragma unroll
  for (int tile = 0; tile < 8; tile++) {
    union { unsigned short u[4]; uint2 v; } pk;
#pragma unroll
    for (int i = 0; i < 4; i++) pk.u[i] = f2bf(vals[tile][i] * inv);
    *(uint2*)&feat[(size_t)q * 128 + tile * 16 + tile * 0 + lg * 4] = pk.v;
  }
}

// ---------------- InfoNCE v4: block = 4 waves sharing a double-buffered LDS B-chunk
// (fragment-major layout, conflict-free b128). Wave owns 64 rows (A resident in regs).
// Flat grid 600: b = id%8 pins each batch to one XCD (L2 locality); 5 colgroups x 15 chunks.
__global__ __launch_bounds__(256, 2) void infonce_kernel(
    const unsigned short* __restrict__ fo, const unsigned short* __restrict__ ft,
    float* __restrict__ sumexp) {
  __shared__ __align__(16) unsigned short Bs[2][6144];   // 2 x 12,288 B
  const int id = blockIdx.x;
  const int b = id & 7;                 // XCD-aligned batch
  const int within = id >> 3;           // 0..74
  const int rowblk = within % 15;
  const int colg = within / 15;         // 0..4
  const int t = threadIdx.x;
  const int w = t >> 6;
  const int lane = t & 63;
  const int lr = lane & 15;
  const int lkq = lane >> 4;            // 0..3
  const int base = rowblk * 256 + w * 64;
  const unsigned short* fob = fo + (size_t)b * HW * 128;
  const unsigned short* ftb = ft + (size_t)b * HW * 128;

  // A fragments: 64 rows resident (clamped; atomics masked later)
  bf16x8 a[4][4];                       // [tile][kk]
#pragma unroll
  for (int tile = 0; tile < 4; tile++) {
    const int r = min(base + tile * 16 + lr, HW - 1);
    const unsigned short* ap = fob + (size_t)r * 128 + lkq * 8;
#pragma unroll
    for (int kk = 0; kk < 4; kk++) a[tile][kk] = *(const bf16x8*)(ap + kk * 32);
  }
  float rs[4][4];
#pragma unroll
  for (int tile = 0; tile < 4; tile++)
#pragma unroll
    for (int i = 0; i < 4; i++) rs[tile][i] = 0.f;

  // staging gather offsets: this thread stages frags f = {w, w+4, w+8};
  // frag f=(kk*3+sub), slot lane holds ft[cbase+sub*16+(lane&15)][kk*32+(lane>>4)*8 ..+7]
  int rowoff[3];
#pragma unroll
  for (int i = 0; i < 3; i++) {
    const int f = i * 4 + w;
    const int kk = f / 3;
    const int sub = f - kk * 3;
    rowoff[i] = (sub * 16 + lr) * 128 + kk * 32 + lkq * 8;
  }

  uint4 r[3];
  {
    const unsigned short* p = ftb + (size_t)(colg * 15) * 48 * 128;
#pragma unroll
    for (int i = 0; i < 3; i++) r[i] = *(const uint4*)(p + rowoff[i]);
  }

  for (int it = 0; it < 15; it++) {
    unsigned short* bufp = &Bs[it & 1][0];
#pragma unroll
    for (int i = 0; i < 3; i++)
      *(uint4*)&bufp[(i * 4 + w) * 512 + lane * 8] = r[i];   // waits vmcnt on r
    __syncthreads();
    if (it < 14) {                      // prefetch next chunk, hides under compute
      const unsigned short* p = ftb + (size_t)((colg * 15 + it + 1)) * 48 * 128;
#pragma unroll
      for (int i = 0; i < 3; i++) r[i] = *(const uint4*)(p + rowoff[i]);
    }
    f32x4 acc[4][3];
#pragma unroll
    for (int tile = 0; tile < 4; tile++)
#pragma unroll
      for (int sub = 0; sub < 3; sub++) acc[tile][sub] = (f32x4){0.f, 0.f, 0.f, 0.f};
#pragma unroll
    for (int kk = 0; kk < 4; kk++) {
      bf16x8 bv[3];
#pragma unroll
      for (int sub = 0; sub < 3; sub++)
        bv[sub] = *(const bf16x8*)&bufp[(kk * 3 + sub) * 512 + lane * 8];
#pragma unroll
      for (int tile = 0; tile < 4; tile++)
#pragma unroll
        for (int sub = 0; sub < 3; sub++)
          acc[tile][sub] = __builtin_amdgcn_mfma_f32_16x16x32_bf16(
              a[tile][kk], bv[sub], acc[tile][sub], 0, 0, 0);
    }
#pragma unroll
    for (int tile = 0; tile < 4; tile++)
#pragma unroll
      for (int sub = 0; sub < 3; sub++)
#pragma unroll
        for (int i = 0; i < 4; i++)
          rs[tile][i] += exp2f(fmaf(acc[tile][sub][i], LOG2E, NM));
    // no second barrier needed: next iter writes the other buffer; its single
    // barrier orders those writes after every wave's reads of that buffer.
  }

  // reduce col-partials over lanes 0-15 of each group
#pragma unroll
  for (int tile = 0; tile < 4; tile++)
#pragma unroll
    for (int i = 0; i < 4; i++) {
      float v = rs[tile][i];
      v += __shfl_xor(v, 1); v += __shfl_xor(v, 2);
      v += __shfl_xor(v, 4); v += __shfl_xor(v, 8);
      rs[tile][i] = v;
    }
  if (lr == 0) {
#pragma unroll
    for (int tile = 0; tile < 4; tile++)
#pragma unroll
      for (int i = 0; i < 4; i++) {
        const int rr = base + tile * 16 + lkq * 4 + i;
        if (rr < HW) atomicAdd(&sumexp[b * HW + rr], rs[tile][i]);
      }
  }
}

// ---------------- final: mean over q of (log(sumexp)+1/T - dot')   [dot' already /T]
__global__ __launch_bounds__(256) void final_kernel(
    const float* __restrict__ sumexp, const unsigned short* __restrict__ fo,
    const unsigned short* __restrict__ ft, float* __restrict__ out) {
  const int q = blockIdx.x * 256 + threadIdx.x;
  float val = 0.f;
  if (q < NQ) {
    const unsigned short* a = fo + (size_t)q * 128;
    const unsigned short* c = ft + (size_t)q * 128;
    float dot = 0.f;
#pragma unroll
    for (int k = 0; k < 128; k += 8) {
      bf16x8 ua = *(const bf16x8*)(a + k);
      bf16x8 ub = *(const bf16x8*)(c + k);
#pragma unroll
      for (int e = 0; e < 8; e++)
        dot = fmaf(bf2f((unsigned short)ua[e]), bf2f((unsigned short)ub[e]), dot);
    }
    val = logf(sumexp[q]) + INV_T - dot;
  }
#pragma unroll
  for (int m = 1; m < 64; m <<= 1) val += __shfl_xor(val, m);
  __shared__ float red[4];
  const int wid = threadIdx.x >> 6;
  if ((threadIdx.x & 63) == 0) red[wid] = val;
  __syncthreads();
  if (threadIdx.x == 0)
    atomicAdd(out, (red[0] + red[1] + red[2] + red[3]) * (1.f / (float)NQ));
}

extern "C" void kernel_launch(void* const* d_in, const int* in_sizes, int n_in,
                              void* d_out, int out_size, void* d_ws, size_t ws_size,
                              hipStream_t stream) {
  (void)in_sizes; (void)n_in; (void)out_size; (void)ws_size;
  const float* x_orig = (const float*)d_in[0];
  const float* x_trans = (const float*)d_in[1];
  const float* conv_w = (const float*)d_in[2];
  const float* conv_b = (const float*)d_in[3];
  const float* gamma = (const float*)d_in[4];
  const float* beta = (const float*)d_in[5];
  const float* lin_w = (const float*)d_in[6];
  const float* lin_b = (const float*)d_in[7];
  float* out = (float*)d_out;

  char* ws = (char*)d_ws;
  unsigned short* yt = (unsigned short*)(ws + 0);            // 2 x 7,372,800 B
  unsigned short* cw16 = (unsigned short*)(ws + 14745600);   //     65,536 B
  unsigned short* lw16 = (unsigned short*)(ws + 14811136);   //     32,768 B
  float* stats = (float*)(ws + 14843904);                    //     32,768 B (2 x 16 x 256)
  float* sc = (float*)(ws + 14876672);                       //      2,048 B
  float* sumexp = (float*)(ws + 14878720);                   //    115,200 B
  unsigned short* feat_o = (unsigned short*)(ws + 14993920); //  7,372,800 B
  unsigned short* feat_t = (unsigned short*)(ws + 22366720); //  7,372,800 B
  // end: 29,739,520 B

  hipMemsetAsync(ws + 14843904, 0, 32768 + 2048 + 115200, stream);  // stats+sc+sumexp
  hipMemsetAsync(d_out, 0, sizeof(float), stream);

  prep_kernel<<<128, 256, 0, stream>>>(conv_w, lin_w, cw16, lw16);

  conv1_mfma_kernel<<<dim3(450, 1, 2), 256, 0, stream>>>(x_orig, x_trans, cw16, yt, stats);
  scale_kernel<<<2, 128, 0, stream>>>(stats, conv_b, gamma, beta, sc);
  conv2_mfma_kernel<<<dim3(450, 1, 2), 256, 0, stream>>>(yt, lw16, sc, lin_b, feat_o, feat_t);

  infonce_kernel<<<600, 256, 0, stream>>>(feat_o, feat_t, sumexp);
  final_kernel<<<113, 256, 0, stream>>>(sumexp, feat_o, feat_t, out);
}